// Round 15
// baseline (371.168 us; speedup 1.0000x reference)
//
#include <hip/hip_runtime.h>
#include <math.h>

#define CC 8
#define FF 1024
#define WW 512
#define HH 16
#define DD 64
#define FE 4096
#define EPS_ 1e-5f

typedef __attribute__((ext_vector_type(8))) short bf16x8;
typedef __attribute__((ext_vector_type(4))) float f32x4;

static __device__ __forceinline__ unsigned short f2bf(float f) {
    unsigned u = __float_as_uint(f);
    u += 0x7fffu + ((u >> 16) & 1u);          // round-to-nearest-even
    return (unsigned short)(u >> 16);
}
static __device__ __forceinline__ float bf2f(unsigned short h) {
    return __uint_as_float(((unsigned)h) << 16);
}
static __device__ __forceinline__ float gelu_exact(float v) {
    return 0.5f * v * (1.0f + erff(v * 0.70710678118654752f));
}
// packed f32x2 -> bf16x2 (RNE), 1 VALU inst; lo -> bits[15:0]
static __device__ __forceinline__ unsigned cvt_pk_bf16(float lo, float hi) {
    unsigned r;
    asm("v_cvt_pk_bf16_f32 %0, %1, %2" : "=v"(r) : "v"(lo), "v"(hi));
    return r;
}

typedef const __attribute__((address_space(1))) unsigned int* gas_p;
typedef __attribute__((address_space(3))) unsigned int* las_p;
static __device__ __forceinline__ void gload_lds16(const void* g, void* l) {
    __builtin_amdgcn_global_load_lds((gas_p)g, (las_p)l, 16, 0, 0);
}

// ---------------------------------------------------------------------------
// frame_norm stage 1: partial (sum, sumsq) per (c,w) over 128-f slabs.
// ---------------------------------------------------------------------------
__global__ __launch_bounds__(256) void fn_stats_k(
    const float* __restrict__ x, float2* __restrict__ part)
{
    int c  = blockIdx.z;
    int w0 = blockIdx.x * 64;
    int f0 = blockIdx.y * 128;
    int t  = threadIdx.x, wl = t & 63, fg = t >> 6;
    const float* xc = x + (size_t)c * FF * WW;

    float s = 0.f, q = 0.f;
    #pragma unroll 8
    for (int i = 0; i < 32; i++) {
        int f = f0 + fg + 4 * i;
        float v = xc[(size_t)f * WW + w0 + wl];
        s += v; q += v * v;
    }
    __shared__ float ss[4][64], sq_[4][64];
    ss[fg][wl] = s; sq_[fg][wl] = q;
    __syncthreads();
    if (fg == 0) {
        float S = 0.f, Q = 0.f;
        #pragma unroll
        for (int j = 0; j < 4; j++) { S += ss[j][wl]; Q += sq_[j][wl]; }
        part[((size_t)c * WW + w0 + wl) * 8 + blockIdx.y] = make_float2(S, Q);
    }
}

// ---------------------------------------------------------------------------
// frame_norm stage 2: finalize stats, normalize, transpose -> zt (c,w,f) bf16
// ---------------------------------------------------------------------------
__global__ __launch_bounds__(256) void fn_apply_k(
    const float* __restrict__ x, const float2* __restrict__ part,
    const float* __restrict__ g, const float* __restrict__ b,
    unsigned short* __restrict__ zt)
{
    int c  = blockIdx.z;
    int w0 = blockIdx.x * 64;
    int f0 = blockIdx.y * 64;
    int t  = threadIdx.x, wl = t & 63, fg = t >> 6;

    __shared__ float smu[64], srv[64];
    __shared__ float sT[64][65];

    if (t < 64) {
        float S = 0.f, Q = 0.f;
        #pragma unroll
        for (int fs = 0; fs < 8; fs++) {
            float2 v = part[((size_t)c * WW + w0 + t) * 8 + fs];
            S += v.x; Q += v.y;
        }
        float mu  = S * (1.f / FF);
        float var = Q * (1.f / FF) - mu * mu;
        smu[t] = mu;
        srv[t] = rsqrtf(var + EPS_);
    }
    const float* xc = x + (size_t)c * FF * WW;
    #pragma unroll
    for (int i = 0; i < 16; i++) {
        int fl = fg * 16 + i;
        sT[fl][wl] = xc[(size_t)(f0 + fl) * WW + w0 + wl];
    }
    __syncthreads();

    unsigned short* ztc = zt + (size_t)c * WW * FF;
    float gv = g[f0 + wl], bv = b[f0 + wl];
    #pragma unroll
    for (int i = 0; i < 16; i++) {
        int wr = fg * 16 + i;
        ztc[(size_t)(w0 + wr) * FF + f0 + wl] =
            f2bf((sT[wl][wr] - smu[wr]) * srv[wr] * gv + bv);
    }
}

// ---------------------------------------------------------------------------
// GEMM v6 (round-9 proven): BM x 128, BK=64, counted vmcnt. For wq / wo.
// ---------------------------------------------------------------------------
template<int BM, int MINW>
__global__ __launch_bounds__(256, MINW) void gemm_v6_k(
    const float* __restrict__ A, const unsigned short* __restrict__ Bt,
    float* __restrict__ Outf, unsigned short* __restrict__ Outb,
    const float* __restrict__ Add, int M, int K, int mode)
{
    constexpr int L  = BM / 16;
    constexpr int MI = BM / 32;
    constexpr int AP = 72;

    int bid = blockIdx.x;
    int c   = bid & 7;
    int rem = bid >> 3;
    int nt  = rem & 3;
    int mt  = rem >> 2;
    int m0  = mt * BM, n0 = nt * 128;
    const float*          Ac = A  + (size_t)c * M * K;
    const unsigned short* Bc = Bt + ((size_t)c * 512 + n0) * K;

    __shared__ unsigned short sA[2][BM * AP];
    __shared__ unsigned short sB[2][128 * 64];

    int t    = threadIdx.x;
    int lane = t & 63;
    int wid  = t >> 6;
    int frl  = lane & 15, fgr = lane >> 4;
    int WM   = (wid >> 1) * (MI * 16);
    int WN   = (wid & 1) * 64;

    f32x4 acc[MI][4];
    #pragma unroll
    for (int i = 0; i < MI; i++)
        #pragma unroll
        for (int j = 0; j < 4; j++) acc[i][j] = (f32x4){0.f, 0.f, 0.f, 0.f};

    int arow = t >> 4;
    int acol = (t & 15) * 4;
    float4 ar[L];

    int bro   = lane >> 3;
    int bslot = (lane & 7) ^ bro;

    auto loadA = [&](int k0) {
        #pragma unroll
        for (int p = 0; p < L; p++)
            ar[p] = *reinterpret_cast<const float4*>(
                Ac + (size_t)(m0 + p * 16 + arow) * K + k0 + acol);
    };
    auto cvtWriteA = [&](int buf) {
        #pragma unroll
        for (int p = 0; p < L; p++) {
            uint2 u;
            u.x = cvt_pk_bf16(ar[p].x, ar[p].y);
            u.y = cvt_pk_bf16(ar[p].z, ar[p].w);
            *reinterpret_cast<uint2*>(&sA[buf][(p * 16 + arow) * AP + acol]) = u;
        }
    };
    auto stageB = [&](int buf, int k0) {
        #pragma unroll
        for (int r = 0; r < 4; r++) {
            int rbase = wid * 32 + r * 8;
            gload_lds16(Bc + (size_t)(rbase + bro) * K + k0 + bslot * 8,
                        &sB[buf][rbase * 64]);
        }
    };

    loadA(0);
    asm volatile("s_waitcnt vmcnt(0)" ::: "memory");
    cvtWriteA(0);
    stageB(0, 0);

    int NT = K >> 6;
    for (int kt = 0; kt < NT; ++kt) {
        int  cur  = kt & 1;
        bool more = (kt + 1 < NT);

        if (more) loadA((kt + 1) << 6);
        if (more) {
            if constexpr (BM == 128)
                asm volatile("s_waitcnt vmcnt(8)" ::: "memory");
            else
                asm volatile("s_waitcnt vmcnt(4)" ::: "memory");
        } else {
            asm volatile("s_waitcnt vmcnt(0)" ::: "memory");
        }
        asm volatile("s_waitcnt lgkmcnt(0)" ::: "memory");
        __builtin_amdgcn_sched_barrier(0);
        __builtin_amdgcn_s_barrier();

        if (more) stageB(cur ^ 1, (kt + 1) << 6);

        #pragma unroll
        for (int ks = 0; ks < 2; ks++) {
            bf16x8 af[MI], bfv[4];
            #pragma unroll
            for (int mi = 0; mi < MI; mi++)
                af[mi] = *reinterpret_cast<const bf16x8*>(
                    &sA[cur][(WM + mi * 16 + frl) * AP + ks * 32 + fgr * 8]);
            #pragma unroll
            for (int ni = 0; ni < 4; ni++) {
                int row  = WN + ni * 16 + frl;
                int slot = ((ks << 2) | fgr) ^ (frl & 7);
                bfv[ni] = *reinterpret_cast<const bf16x8*>(
                    &sB[cur][row * 64 + slot * 8]);
            }
            #pragma unroll
            for (int mi = 0; mi < MI; mi++)
                #pragma unroll
                for (int ni = 0; ni < 4; ni++)
                    acc[mi][ni] = __builtin_amdgcn_mfma_f32_16x16x32_bf16(
                        af[mi], bfv[ni], acc[mi][ni], 0, 0, 0);
        }

        if (more) {
            asm volatile("s_waitcnt vmcnt(4)" ::: "memory");
            __builtin_amdgcn_sched_barrier(0);
            cvtWriteA(cur ^ 1);
        }
    }

    if (mode == 1) {
        #pragma unroll
        for (int mi = 0; mi < MI; mi++)
            #pragma unroll
            for (int ni = 0; ni < 4; ni++) {
                int mrow = m0 + WM + mi * 16 + fgr * 4;
                int ncol = n0 + WN + ni * 16 + frl;
                #pragma unroll
                for (int r = 0; r < 4; r++) {
                    size_t o = ((size_t)c * M + mrow + r) * 512 + ncol;
                    Outf[o] = acc[mi][ni][r] + Add[o];
                }
            }
    } else {
        bool gel = (mode == 2);
        #pragma unroll
        for (int mi = 0; mi < MI; mi++)
            #pragma unroll
            for (int ni = 0; ni < 4; ni++) {
                f32x4 v = acc[mi][ni];
                if (gel) {
                    v[0] = gelu_exact(v[0]); v[1] = gelu_exact(v[1]);
                    v[2] = gelu_exact(v[2]); v[3] = gelu_exact(v[3]);
                }
                int mrow = m0 + WM + mi * 16 + fgr * 4;
                int ncol = n0 + WN + ni * 16 + frl;
                ushort4 h;
                h.x = f2bf(v[0]); h.y = f2bf(v[1]);
                h.z = f2bf(v[2]); h.w = f2bf(v[3]);
                *reinterpret_cast<ushort4*>(
                    &Outb[((size_t)c * 512 + ncol) * M + mrow]) = h;
            }
    }
}

// ---------------------------------------------------------------------------
// GEMM wave-free: BARRIER-FREE wave-autonomous tiles. Each wave owns a
// (MI*16)m x (NI*16)n output tile over full K; all LDS is wave-private, so
// NO __syncthreads / s_barrier exist — waves self-pace on their own vmcnt/
// lgkmcnt and the CU scheduler interleaves out-of-phase waves (m114
// mechanism without lockstep). BK=32.
//  - B: wave-private single-buffered LDS tile via gload_lds, 4-slot XOR
//    involution swizzle (proven v8 geometry). Overwrite-safe: same-wave
//    lgkmcnt(0) after frag reads precedes next stage (DS FIFO is in-order).
//  - A: double reg-set + cvt_pk -> wave-private sA dbuf (pitch 40, proven).
//  - Ledger/wave (L A-loads, G B-gloads): steady [B(t)G, A(t+1)L];
//    top vmcnt(L) retires B(t); after stageB(t+1): vmcnt(G) retires A(t+1);
//    then loadA(t+2). A (HBM stream) gets 2-iter cover, B (L2) ~0.7.
// MODE 1: fp32 (c,m,n)+Add;  MODE 2: GELU + bf16 transposed (c,n,m).
// Grid: bid = c + 8*(nt + NTn*mtb); block = 4 waves at m = mtb*4+wid tiles.
// ---------------------------------------------------------------------------
template<int MI, int NI, int MODE>
__global__ __launch_bounds__(256, 2) void gemm_wfree_k(
    const float* __restrict__ A, const unsigned short* __restrict__ Bt,
    float* __restrict__ Outf, unsigned short* __restrict__ Outb,
    const float* __restrict__ Add, int M, int K)
{
    constexpr int R   = MI * 16;       // A rows per wave
    constexpr int BN  = NI * 16;       // n cols per wave
    constexpr int L   = R / 8;         // A float4 loads / lane / tile
    constexpr int G   = NI;            // B gloads / wave / tile
    constexpr int NTn = 512 / BN;
    constexpr int LPR = 64 / R;        // lanes per A row
    constexpr int FPL = 32 / LPR;      // floats per lane per A row

    int bid = blockIdx.x;
    int c   = bid & 7;
    int rem = bid >> 3;
    int nt  = rem & (NTn - 1);
    int mtb = rem / NTn;

    int t    = threadIdx.x;
    int lane = t & 63;
    int wid  = t >> 6;
    int m0w  = (mtb * 4 + wid) * R;
    int n0   = nt * BN;

    const float*          Ac = A  + (size_t)c * M * K;
    const unsigned short* Bc = Bt + ((size_t)c * 512 + n0) * K;

    __shared__ unsigned short sB[4][BN * 32];      // wave-private slices
    __shared__ unsigned short sA[4][2][R * 40];
    unsigned short* sBw = sB[wid];

    int frl  = lane & 15, fgr = lane >> 4;
    int arow = lane / LPR, asub = lane % LPR;
    int bro  = lane >> 2;
    int bslot = (lane & 3) ^ (bro & 3);

    f32x4 acc[MI][NI];
    #pragma unroll
    for (int i = 0; i < MI; i++)
        #pragma unroll
        for (int j = 0; j < NI; j++) acc[i][j] = (f32x4){0.f, 0.f, 0.f, 0.f};

    float4 ar0[L], ar1[L];

    auto loadAinto = [&](int k0, float4 (&ar)[L]) {
        #pragma unroll
        for (int p = 0; p < L; p++)
            ar[p] = *reinterpret_cast<const float4*>(
                Ac + (size_t)(m0w + arow) * K + k0 + asub * FPL + p * 4);
    };
    auto cvtWriteA = [&](int buf, float4 (&ar)[L]) {
        #pragma unroll
        for (int p = 0; p < L; p++) {
            uint2 u;
            u.x = cvt_pk_bf16(ar[p].x, ar[p].y);
            u.y = cvt_pk_bf16(ar[p].z, ar[p].w);
            *reinterpret_cast<uint2*>(
                &sA[wid][buf][arow * 40 + asub * FPL + p * 4]) = u;
        }
    };
    auto stageB = [&](int k0) {
        #pragma unroll
        for (int r = 0; r < G; r++)
            gload_lds16(Bc + (size_t)(r * 16 + bro) * K + k0 + bslot * 8,
                        &sBw[r * 512]);
    };

    int NT = K >> 5;   // 32 (K=1024) or 128 (K=4096) — even

    // prologue: A0 -> sA[0]; B0 + A1 in flight. Invariant: [B(t)G, A(t+1)L]
    loadAinto(0, ar0);
    asm volatile("s_waitcnt vmcnt(0)" ::: "memory");
    __builtin_amdgcn_sched_barrier(0);
    cvtWriteA(0, ar0);
    stageB(0);
    loadAinto(32, ar1);

    auto body = [&](int kt, float4 (&arW)[L], float4 (&arR)[L]) {
        bool more1 = (kt + 1 < NT), more2 = (kt + 2 < NT);
        int  cur   = kt & 1;

        // retire B(kt); keep A(kt+1) in flight
        if (more1) asm volatile("s_waitcnt vmcnt(%0)" :: "i"(L) : "memory");
        else       asm volatile("s_waitcnt vmcnt(0)" ::: "memory");
        __builtin_amdgcn_sched_barrier(0);

        bf16x8 af[MI], bfv[NI];
        #pragma unroll
        for (int mi = 0; mi < MI; mi++)
            af[mi] = *reinterpret_cast<const bf16x8*>(
                &sA[wid][cur][(mi * 16 + frl) * 40 + fgr * 8]);
        #pragma unroll
        for (int ni = 0; ni < NI; ni++) {
            int row  = ni * 16 + frl;
            int slot = fgr ^ (row & 3);
            bfv[ni] = *reinterpret_cast<const bf16x8*>(
                &sBw[row * 32 + slot * 8]);
        }
        asm volatile("s_waitcnt lgkmcnt(0)" ::: "memory");   // frags in regs
        __builtin_amdgcn_sched_barrier(0);

        if (more1) {
            stageB((kt + 1) << 5);                 // safe: B(kt) reads done
            asm volatile("s_waitcnt vmcnt(%0)" :: "i"(G) : "memory");
            __builtin_amdgcn_sched_barrier(0);
            cvtWriteA(cur ^ 1, arR);               // A(kt+1) -> other buf
            if (more2) loadAinto((kt + 2) << 5, arW);
        }

        #pragma unroll
        for (int mi = 0; mi < MI; mi++)
            #pragma unroll
            for (int ni = 0; ni < NI; ni++)
                acc[mi][ni] = __builtin_amdgcn_mfma_f32_16x16x32_bf16(
                    af[mi], bfv[ni], acc[mi][ni], 0, 0, 0);
    };

    for (int kt = 0; kt < NT; kt += 2) {
        body(kt,     ar0, ar1);
        body(kt + 1, ar1, ar0);
    }

    // epilogue. C/D: col = lane&15, row = (lane>>4)*4 + reg
    if constexpr (MODE == 1) {
        #pragma unroll
        for (int mi = 0; mi < MI; mi++)
            #pragma unroll
            for (int ni = 0; ni < NI; ni++) {
                int mrow = m0w + mi * 16 + fgr * 4;
                int ncol = n0 + ni * 16 + frl;
                #pragma unroll
                for (int r = 0; r < 4; r++) {
                    size_t o = ((size_t)c * M + mrow + r) * 512 + ncol;
                    Outf[o] = acc[mi][ni][r] + Add[o];
                }
            }
    } else {
        #pragma unroll
        for (int mi = 0; mi < MI; mi++)
            #pragma unroll
            for (int ni = 0; ni < NI; ni++) {
                f32x4 v = acc[mi][ni];
                v[0] = gelu_exact(v[0]); v[1] = gelu_exact(v[1]);
                v[2] = gelu_exact(v[2]); v[3] = gelu_exact(v[3]);
                int mrow = m0w + mi * 16 + fgr * 4;
                int ncol = n0 + ni * 16 + frl;
                ushort4 h;
                h.x = f2bf(v[0]); h.y = f2bf(v[1]);
                h.z = f2bf(v[2]); h.w = f2bf(v[3]);
                *reinterpret_cast<ushort4*>(
                    &Outb[((size_t)c * 512 + ncol) * M + mrow]) = h;
            }
    }
}

// ---------------------------------------------------------------------------
// MFMA flash attention (unchanged from round 3).
// ---------------------------------------------------------------------------
__global__ __launch_bounds__(256) void attn_mfma_k(
    const unsigned short* __restrict__ pt, const float* __restrict__ fr,
    unsigned short* __restrict__ ot)
{
    int ch = blockIdx.y;
    int c  = ch >> 4, h = ch & 15;
    int q0 = blockIdx.x * 64;
    int t  = threadIdx.x;
    int lane = t & 63;
    int wid  = t >> 6;
    int frl  = lane & 15, fgr = lane >> 4;

    const unsigned short* base = pt + (size_t)c * WW * FF + h * DD;

    __shared__ unsigned short Qs[64 * 72];
    __shared__ unsigned short Ks[64 * 72];
    __shared__ unsigned short Vt[64 * 72];
    __shared__ unsigned short Ps[4 * 16 * 72];

    {
        int kr = t >> 3, d0 = (t & 7) * 8;
        #pragma unroll
        for (int r = 0; r < 2; r++) {
            int row = kr + r * 32;
            int w   = q0 + row;
            bf16x8 v = *reinterpret_cast<const bf16x8*>(&base[(size_t)w * FF + d0]);
            bf16x8 o;
            if (d0 < 32) {
                #pragma unroll
                for (int j = 0; j < 8; j += 2) {
                    float x1 = bf2f((unsigned short)v[j]);
                    float x2 = bf2f((unsigned short)v[j + 1]);
                    float sn, cs;
                    __sincosf((float)w * fr[(d0 + j) >> 1], &sn, &cs);
                    o[j]     = (short)f2bf(x1 * cs - x2 * sn);
                    o[j + 1] = (short)f2bf(x2 * cs + x1 * sn);
                }
            } else o = v;
            *reinterpret_cast<bf16x8*>(&Qs[row * 72 + d0]) = o;
        }
    }

    f32x4 oacc[4];
    float m_[4], l_[4];
    #pragma unroll
    for (int i = 0; i < 4; i++) {
        oacc[i] = (f32x4){0.f, 0.f, 0.f, 0.f};
        m_[i] = -1e30f; l_[i] = 0.f;
    }
    unsigned short* myP = &Ps[wid * 16 * 72];
    int wq0 = wid * 16;

    for (int k0 = 0; k0 < WW; k0 += 64) {
        __syncthreads();
        {
            int kr = t >> 3, d0 = (t & 7) * 8;
            #pragma unroll
            for (int r = 0; r < 2; r++) {
                int row = kr + r * 32;
                int w   = k0 + row;
                bf16x8 v = *reinterpret_cast<const bf16x8*>(&base[(size_t)w * FF + d0]);
                bf16x8 o;
                if (d0 < 32) {
                    #pragma unroll
                    for (int j = 0; j < 8; j += 2) {
                        float x1 = bf2f((unsigned short)v[j]);
                        float x2 = bf2f((unsigned short)v[j + 1]);
                        float sn, cs;
                        __sincosf((float)w * fr[(d0 + j) >> 1], &sn, &cs);
                        o[j]     = (short)f2bf(x1 * cs - x2 * sn);
                        o[j + 1] = (short)f2bf(x2 * cs + x1 * sn);
                    }
                } else o = v;
                *reinterpret_cast<bf16x8*>(&Ks[row * 72 + d0]) = o;
            }
        }
        {
            int d  = t & 63;
            int kb = (t >> 6) * 8;
            #pragma unroll
            for (int r = 0; r < 2; r++) {
                int kk = kb + r * 32;
                bf16x8 o;
                #pragma unroll
                for (int j = 0; j < 8; j++)
                    o[j] = (short)base[(size_t)(k0 + kk + j) * FF + d];
                *reinterpret_cast<bf16x8*>(&Vt[d * 72 + kk]) = o;
            }
        }
        __syncthreads();

        f32x4 s[4];
        #pragma unroll
        for (int nt = 0; nt < 4; nt++) s[nt] = (f32x4){0.f, 0.f, 0.f, 0.f};
        bf16x8 aq0 = *reinterpret_cast<const bf16x8*>(&Qs[(wq0 + frl) * 72 + fgr * 8]);
        bf16x8 aq1 = *reinterpret_cast<const bf16x8*>(&Qs[(wq0 + frl) * 72 + 32 + fgr * 8]);
        #pragma unroll
        for (int nt = 0; nt < 4; nt++) {
            bf16x8 b0 = *reinterpret_cast<const bf16x8*>(&Ks[(nt * 16 + frl) * 72 + fgr * 8]);
            bf16x8 b1 = *reinterpret_cast<const bf16x8*>(&Ks[(nt * 16 + frl) * 72 + 32 + fgr * 8]);
            s[nt] = __builtin_amdgcn_mfma_f32_16x16x32_bf16(aq0, b0, s[nt], 0, 0, 0);
            s[nt] = __builtin_amdgcn_mfma_f32_16x16x32_bf16(aq1, b1, s[nt], 0, 0, 0);
        }

        #pragma unroll
        for (int r = 0; r < 4; r++) {
            float sv[4];
            #pragma unroll
            for (int nt = 0; nt < 4; nt++) sv[nt] = s[nt][r] * (1.f / 32.f);
            float mx = fmaxf(fmaxf(sv[0], sv[1]), fmaxf(sv[2], sv[3]));
            mx = fmaxf(mx, __shfl_xor(mx, 1, 64));
            mx = fmaxf(mx, __shfl_xor(mx, 2, 64));
            mx = fmaxf(mx, __shfl_xor(mx, 4, 64));
            mx = fmaxf(mx, __shfl_xor(mx, 8, 64));
            float mn    = fmaxf(m_[r], mx);
            float scale = __expf(m_[r] - mn);
            float rs = 0.f;
            #pragma unroll
            for (int nt = 0; nt < 4; nt++) {
                float p = __expf(sv[nt] - mn);
                myP[(fgr * 4 + r) * 72 + nt * 16 + frl] = f2bf(p);
                rs += p;
            }
            rs += __shfl_xor(rs, 1, 64);
            rs += __shfl_xor(rs, 2, 64);
            rs += __shfl_xor(rs, 4, 64);
            rs += __shfl_xor(rs, 8, 64);
            l_[r] = l_[r] * scale + rs;
            m_[r] = mn;
            #pragma unroll
            for (int dt = 0; dt < 4; dt++) oacc[dt][r] *= scale;
        }

        bf16x8 ap0 = *reinterpret_cast<const bf16x8*>(&myP[frl * 72 + fgr * 8]);
        bf16x8 ap1 = *reinterpret_cast<const bf16x8*>(&myP[frl * 72 + 32 + fgr * 8]);
        #pragma unroll
        for (int dt = 0; dt < 4; dt++) {
            bf16x8 b0 = *reinterpret_cast<const bf16x8*>(&Vt[(dt * 16 + frl) * 72 + fgr * 8]);
            bf16x8 b1 = *reinterpret_cast<const bf16x8*>(&Vt[(dt * 16 + frl) * 72 + 32 + fgr * 8]);
            oacc[dt] = __builtin_amdgcn_mfma_f32_16x16x32_bf16(ap0, b0, oacc[dt], 0, 0, 0);
            oacc[dt] = __builtin_amdgcn_mfma_f32_16x16x32_bf16(ap1, b1, oacc[dt], 0, 0, 0);
        }
    }

    unsigned short* ob = ot + (size_t)c * WW * FF + h * DD;
    #pragma unroll
    for (int r = 0; r < 4; r++) {
        float inv = 1.f / l_[r];
        int w = q0 + wq0 + fgr * 4 + r;
        #pragma unroll
        for (int dt = 0; dt < 4; dt++)
            ob[(size_t)w * FF + dt * 16 + frl] = f2bf(oacc[dt][r] * inv);
    }
}

// ---------------------------------------------------------------------------
extern "C" void kernel_launch(void* const* d_in, const int* in_sizes, int n_in,
                              void* d_out, int out_size, void* d_ws, size_t ws_size,
                              hipStream_t stream)
{
    const float* x  = (const float*)d_in[0];
    const float* g1 = (const float*)d_in[1];
    const float* b1 = (const float*)d_in[2];
    const float* wq = (const float*)d_in[3];
    const float* wo = (const float*)d_in[4];
    const float* fr = (const float*)d_in[5];
    const float* g2 = (const float*)d_in[6];
    const float* b2 = (const float*)d_in[7];
    const float* w1 = (const float*)d_in[8];
    const float* w2 = (const float*)d_in[9];

    const size_t SZ = (size_t)CC * FF * WW;
    char* wsb = (char*)d_ws;
    unsigned short* zt  = (unsigned short*)(wsb);            // bf16 (c,w,f)
    unsigned short* ptb = (unsigned short*)(wsb + 2 * SZ);   // bf16 (c,w,f)
    unsigned short* otb = (unsigned short*)(wsb + 4 * SZ);   // bf16 (c,w,f)
    float*          x2  = (float*)        (wsb + 6 * SZ);    // fp32 (c,f,w)
    unsigned short* h1t = (unsigned short*)(wsb + 10 * SZ);  // bf16 (c,w,4096)
    float2*         prt = (float2*)       (wsb + 18 * SZ);   // stats partials

    dim3 b256(256);
    dim3 gst(WW / 64, FF / 128, CC);
    dim3 gap(WW / 64, FF / 64, CC);

    // 1. zt = frame_norm(x)^T (bf16)
    fn_stats_k<<<gst, b256, 0, stream>>>(x, prt);
    fn_apply_k<<<gap, b256, 0, stream>>>(x, prt, g1, b1, zt);
    // 2. ptb = (wq . z)^T — v6, grid 512
    gemm_v6_k<64, 3><<<dim3(512), b256, 0, stream>>>(
        wq, zt, nullptr, ptb, nullptr, FF, FF, 0);
    // 3. attention (rope fused) -> otb (c,w,f) bf16
    attn_mfma_k<<<dim3(WW / 64, CC * HH), b256, 0, stream>>>(ptb, fr, otb);
    // 4. x2 = x + wo . o — v6
    gemm_v6_k<64, 3><<<dim3(512), b256, 0, stream>>>(
        wo, otb, x2, nullptr, x, FF, FF, 1);
    // 5. zt = frame_norm(x2)^T
    fn_stats_k<<<gst, b256, 0, stream>>>(x2, prt);
    fn_apply_k<<<gap, b256, 0, stream>>>(x2, prt, g2, b2, zt);
    // 6. h1t = gelu(w1 . z2)^T — barrier-free, wave tile 32x128,
    //    grid 8c x 4nt x 32mtb = 1024 blocks (4096 waves)
    gemm_wfree_k<2, 8, 2><<<dim3(1024), b256, 0, stream>>>(
        w1, zt, nullptr, h1t, nullptr, FE, FF);
    // 7. out = x2 + w2 . h1 — barrier-free, wave tile 32x64,
    //    grid 8c x 8nt x 8mtb = 512 blocks (2048 waves), K=4096
    gemm_wfree_k<2, 4, 1><<<dim3(512), b256, 0, stream>>>(
        w2, h1t, (float*)d_out, nullptr, x2, FF, FE);
}

// Round 16
// 259.449 us; speedup vs baseline: 1.4306x; 1.4306x over previous
//
#include <hip/hip_runtime.h>
#include <math.h>

#define CC 8
#define FF 1024
#define WW 512
#define HH 16
#define DD 64
#define FE 4096
#define EPS_ 1e-5f

typedef __attribute__((ext_vector_type(8))) short bf16x8;
typedef __attribute__((ext_vector_type(4))) float f32x4;

static __device__ __forceinline__ unsigned short f2bf(float f) {
    unsigned u = __float_as_uint(f);
    u += 0x7fffu + ((u >> 16) & 1u);          // round-to-nearest-even
    return (unsigned short)(u >> 16);
}
static __device__ __forceinline__ float bf2f(unsigned short h) {
    return __uint_as_float(((unsigned)h) << 16);
}
static __device__ __forceinline__ float gelu_exact(float v) {
    return 0.5f * v * (1.0f + erff(v * 0.70710678118654752f));
}
// packed f32x2 -> bf16x2 (RNE), 1 VALU inst; lo -> bits[15:0]
static __device__ __forceinline__ unsigned cvt_pk_bf16(float lo, float hi) {
    unsigned r;
    asm("v_cvt_pk_bf16_f32 %0, %1, %2" : "=v"(r) : "v"(lo), "v"(hi));
    return r;
}

typedef const __attribute__((address_space(1))) unsigned int* gas_p;
typedef __attribute__((address_space(3))) unsigned int* las_p;
static __device__ __forceinline__ void gload_lds16(const void* g, void* l) {
    __builtin_amdgcn_global_load_lds((gas_p)g, (las_p)l, 16, 0, 0);
}

// ---------------------------------------------------------------------------
// frame_norm stage 1: partial (sum, sumsq) per (c,w) over 128-f slabs.
// ---------------------------------------------------------------------------
__global__ __launch_bounds__(256) void fn_stats_k(
    const float* __restrict__ x, float2* __restrict__ part)
{
    int c  = blockIdx.z;
    int w0 = blockIdx.x * 64;
    int f0 = blockIdx.y * 128;
    int t  = threadIdx.x, wl = t & 63, fg = t >> 6;
    const float* xc = x + (size_t)c * FF * WW;

    float s = 0.f, q = 0.f;
    #pragma unroll 8
    for (int i = 0; i < 32; i++) {
        int f = f0 + fg + 4 * i;
        float v = xc[(size_t)f * WW + w0 + wl];
        s += v; q += v * v;
    }
    __shared__ float ss[4][64], sq_[4][64];
    ss[fg][wl] = s; sq_[fg][wl] = q;
    __syncthreads();
    if (fg == 0) {
        float S = 0.f, Q = 0.f;
        #pragma unroll
        for (int j = 0; j < 4; j++) { S += ss[j][wl]; Q += sq_[j][wl]; }
        part[((size_t)c * WW + w0 + wl) * 8 + blockIdx.y] = make_float2(S, Q);
    }
}

// ---------------------------------------------------------------------------
// frame_norm stage 2: finalize stats, normalize, transpose -> zt (c,w,f) bf16
// ---------------------------------------------------------------------------
__global__ __launch_bounds__(256) void fn_apply_k(
    const float* __restrict__ x, const float2* __restrict__ part,
    const float* __restrict__ g, const float* __restrict__ b,
    unsigned short* __restrict__ zt)
{
    int c  = blockIdx.z;
    int w0 = blockIdx.x * 64;
    int f0 = blockIdx.y * 64;
    int t  = threadIdx.x, wl = t & 63, fg = t >> 6;

    __shared__ float smu[64], srv[64];
    __shared__ float sT[64][65];

    if (t < 64) {
        float S = 0.f, Q = 0.f;
        #pragma unroll
        for (int fs = 0; fs < 8; fs++) {
            float2 v = part[((size_t)c * WW + w0 + t) * 8 + fs];
            S += v.x; Q += v.y;
        }
        float mu  = S * (1.f / FF);
        float var = Q * (1.f / FF) - mu * mu;
        smu[t] = mu;
        srv[t] = rsqrtf(var + EPS_);
    }
    const float* xc = x + (size_t)c * FF * WW;
    #pragma unroll
    for (int i = 0; i < 16; i++) {
        int fl = fg * 16 + i;
        sT[fl][wl] = xc[(size_t)(f0 + fl) * WW + w0 + wl];
    }
    __syncthreads();

    unsigned short* ztc = zt + (size_t)c * WW * FF;
    float gv = g[f0 + wl], bv = b[f0 + wl];
    #pragma unroll
    for (int i = 0; i < 16; i++) {
        int wr = fg * 16 + i;
        ztc[(size_t)(w0 + wr) * FF + f0 + wl] =
            f2bf((sT[wl][wr] - smu[wr]) * srv[wr] * gv + bv);
    }
}

// ---------------------------------------------------------------------------
// GEMM v6 (round-9 proven): BM x 128, BK=64, counted vmcnt.
// Used for wq / wo / w2.
// ---------------------------------------------------------------------------
template<int BM, int MINW>
__global__ __launch_bounds__(256, MINW) void gemm_v6_k(
    const float* __restrict__ A, const unsigned short* __restrict__ Bt,
    float* __restrict__ Outf, unsigned short* __restrict__ Outb,
    const float* __restrict__ Add, int M, int K, int mode)
{
    constexpr int L  = BM / 16;
    constexpr int MI = BM / 32;
    constexpr int AP = 72;

    int bid = blockIdx.x;
    int c   = bid & 7;
    int rem = bid >> 3;
    int nt  = rem & 3;
    int mt  = rem >> 2;
    int m0  = mt * BM, n0 = nt * 128;
    const float*          Ac = A  + (size_t)c * M * K;
    const unsigned short* Bc = Bt + ((size_t)c * 512 + n0) * K;

    __shared__ unsigned short sA[2][BM * AP];
    __shared__ unsigned short sB[2][128 * 64];

    int t    = threadIdx.x;
    int lane = t & 63;
    int wid  = t >> 6;
    int frl  = lane & 15, fgr = lane >> 4;
    int WM   = (wid >> 1) * (MI * 16);
    int WN   = (wid & 1) * 64;

    f32x4 acc[MI][4];
    #pragma unroll
    for (int i = 0; i < MI; i++)
        #pragma unroll
        for (int j = 0; j < 4; j++) acc[i][j] = (f32x4){0.f, 0.f, 0.f, 0.f};

    int arow = t >> 4;
    int acol = (t & 15) * 4;
    float4 ar[L];

    int bro   = lane >> 3;
    int bslot = (lane & 7) ^ bro;

    auto loadA = [&](int k0) {
        #pragma unroll
        for (int p = 0; p < L; p++)
            ar[p] = *reinterpret_cast<const float4*>(
                Ac + (size_t)(m0 + p * 16 + arow) * K + k0 + acol);
    };
    auto cvtWriteA = [&](int buf) {
        #pragma unroll
        for (int p = 0; p < L; p++) {
            uint2 u;
            u.x = cvt_pk_bf16(ar[p].x, ar[p].y);
            u.y = cvt_pk_bf16(ar[p].z, ar[p].w);
            *reinterpret_cast<uint2*>(&sA[buf][(p * 16 + arow) * AP + acol]) = u;
        }
    };
    auto stageB = [&](int buf, int k0) {
        #pragma unroll
        for (int r = 0; r < 4; r++) {
            int rbase = wid * 32 + r * 8;
            gload_lds16(Bc + (size_t)(rbase + bro) * K + k0 + bslot * 8,
                        &sB[buf][rbase * 64]);
        }
    };

    loadA(0);
    asm volatile("s_waitcnt vmcnt(0)" ::: "memory");
    cvtWriteA(0);
    stageB(0, 0);

    int NT = K >> 6;
    for (int kt = 0; kt < NT; ++kt) {
        int  cur  = kt & 1;
        bool more = (kt + 1 < NT);

        if (more) loadA((kt + 1) << 6);
        if (more) {
            if constexpr (BM == 128)
                asm volatile("s_waitcnt vmcnt(8)" ::: "memory");
            else
                asm volatile("s_waitcnt vmcnt(4)" ::: "memory");
        } else {
            asm volatile("s_waitcnt vmcnt(0)" ::: "memory");
        }
        asm volatile("s_waitcnt lgkmcnt(0)" ::: "memory");
        __builtin_amdgcn_sched_barrier(0);
        __builtin_amdgcn_s_barrier();

        if (more) stageB(cur ^ 1, (kt + 1) << 6);

        #pragma unroll
        for (int ks = 0; ks < 2; ks++) {
            bf16x8 af[MI], bfv[4];
            #pragma unroll
            for (int mi = 0; mi < MI; mi++)
                af[mi] = *reinterpret_cast<const bf16x8*>(
                    &sA[cur][(WM + mi * 16 + frl) * AP + ks * 32 + fgr * 8]);
            #pragma unroll
            for (int ni = 0; ni < 4; ni++) {
                int row  = WN + ni * 16 + frl;
                int slot = ((ks << 2) | fgr) ^ (frl & 7);
                bfv[ni] = *reinterpret_cast<const bf16x8*>(
                    &sB[cur][row * 64 + slot * 8]);
            }
            #pragma unroll
            for (int mi = 0; mi < MI; mi++)
                #pragma unroll
                for (int ni = 0; ni < 4; ni++)
                    acc[mi][ni] = __builtin_amdgcn_mfma_f32_16x16x32_bf16(
                        af[mi], bfv[ni], acc[mi][ni], 0, 0, 0);
        }

        if (more) {
            asm volatile("s_waitcnt vmcnt(4)" ::: "memory");
            __builtin_amdgcn_sched_barrier(0);
            cvtWriteA(cur ^ 1);
        }
    }

    if (mode == 1) {
        #pragma unroll
        for (int mi = 0; mi < MI; mi++)
            #pragma unroll
            for (int ni = 0; ni < 4; ni++) {
                int mrow = m0 + WM + mi * 16 + fgr * 4;
                int ncol = n0 + WN + ni * 16 + frl;
                #pragma unroll
                for (int r = 0; r < 4; r++) {
                    size_t o = ((size_t)c * M + mrow + r) * 512 + ncol;
                    Outf[o] = acc[mi][ni][r] + Add[o];
                }
            }
    } else {
        bool gel = (mode == 2);
        #pragma unroll
        for (int mi = 0; mi < MI; mi++)
            #pragma unroll
            for (int ni = 0; ni < 4; ni++) {
                f32x4 v = acc[mi][ni];
                if (gel) {
                    v[0] = gelu_exact(v[0]); v[1] = gelu_exact(v[1]);
                    v[2] = gelu_exact(v[2]); v[3] = gelu_exact(v[3]);
                }
                int mrow = m0 + WM + mi * 16 + fgr * 4;
                int ncol = n0 + WN + ni * 16 + frl;
                ushort4 h;
                h.x = f2bf(v[0]); h.y = f2bf(v[1]);
                h.z = f2bf(v[2]); h.w = f2bf(v[3]);
                *reinterpret_cast<ushort4*>(
                    &Outb[((size_t)c * 512 + ncol) * M + mrow]) = h;
            }
    }
}

// ---------------------------------------------------------------------------
// GEMM w1-big (round-14 proven): block 128m x 256n, BK=32, 4 waves (2m x 2n),
// wave tile 64x128 (acc 4x8). Halves slot count vs v6 for w1's M=4096.
// Staging identical to v8: sA pitch-40 cvt_pk reg-stage; sB gload_lds with
// 4-slot XOR involution; L=4/G=4 counted-vmcnt ledger.
// GELU + bf16 transposed epilogue only (w1's mode).
// Grid: bid = c + 8*(nt + 2*mt), nt over 2, mt over M/128. 512 blocks.
// ---------------------------------------------------------------------------
__global__ __launch_bounds__(256, 2) void gemm_w1big_k(
    const float* __restrict__ A, const unsigned short* __restrict__ Bt,
    unsigned short* __restrict__ Outb, int M, int K)
{
    constexpr int L  = 4;    // A float4 loads / thread / tile (128 rows)
    constexpr int G  = 4;    // B gload_lds / thread / tile (256 rows)
    constexpr int AP = 40;   // sA pitch (elems), proven v8 layout

    int bid = blockIdx.x;
    int c   = bid & 7;
    int rem = bid >> 3;
    int nt  = rem & 1;
    int mt  = rem >> 1;
    int m0  = mt * 128, n0 = nt * 256;
    const float*          Ac = A  + (size_t)c * M * K;
    const unsigned short* Bc = Bt + ((size_t)c * 512 + n0) * K;

    __shared__ unsigned short sA[2][128 * AP];   // 20 KB
    __shared__ unsigned short sB[2][256 * 32];   // 32 KB

    int t    = threadIdx.x;
    int lane = t & 63;
    int wid  = t >> 6;
    int frl  = lane & 15, fgr = lane >> 4;
    int WM   = (wid >> 1) * 64;
    int WN   = (wid & 1) * 128;

    f32x4 acc[4][8];
    #pragma unroll
    for (int i = 0; i < 4; i++)
        #pragma unroll
        for (int j = 0; j < 8; j++) acc[i][j] = (f32x4){0.f, 0.f, 0.f, 0.f};

    int arow = t >> 3;          // 0..31
    int acol = (t & 7) * 4;     // 0..28
    float4 ar[L];

    int bro   = lane >> 2;                    // 0..15 row-in-16 group
    int bslot = (lane & 3) ^ (bro & 3);       // 4-slot involution swizzle

    auto loadA = [&](int k0) {
        #pragma unroll
        for (int p = 0; p < L; p++)
            ar[p] = *reinterpret_cast<const float4*>(
                Ac + (size_t)(m0 + p * 32 + arow) * K + k0 + acol);
    };
    auto cvtWriteA = [&](int buf) {
        #pragma unroll
        for (int p = 0; p < L; p++) {
            uint2 u;
            u.x = cvt_pk_bf16(ar[p].x, ar[p].y);
            u.y = cvt_pk_bf16(ar[p].z, ar[p].w);
            *reinterpret_cast<uint2*>(&sA[buf][(p * 32 + arow) * AP + acol]) = u;
        }
    };
    auto stageB = [&](int buf, int k0) {
        #pragma unroll
        for (int r = 0; r < G; r++) {
            int rbase = wid * 64 + r * 16;
            gload_lds16(Bc + (size_t)(rbase + bro) * K + k0 + bslot * 8,
                        &sB[buf][rbase * 32]);
        }
    };

    // prologue
    loadA(0);
    asm volatile("s_waitcnt vmcnt(0)" ::: "memory");
    cvtWriteA(0);
    stageB(0, 0);

    int NT = K >> 5;   // 32 for K=1024
    for (int kt = 0; kt < NT; ++kt) {
        int  cur  = kt & 1;
        bool more = (kt + 1 < NT);

        if (more) loadA((kt + 1) << 5);      // queue: B(t)G, A(t+1)L
        if (more)
            asm volatile("s_waitcnt vmcnt(4)" ::: "memory");  // retire B(t)
        else
            asm volatile("s_waitcnt vmcnt(0)" ::: "memory");
        asm volatile("s_waitcnt lgkmcnt(0)" ::: "memory");
        __builtin_amdgcn_sched_barrier(0);
        __builtin_amdgcn_s_barrier();

        if (more) stageB(cur ^ 1, (kt + 1) << 5);  // in flight across MFMA

        {
            bf16x8 af[4], bfv[8];
            #pragma unroll
            for (int mi = 0; mi < 4; mi++)
                af[mi] = *reinterpret_cast<const bf16x8*>(
                    &sA[cur][(WM + mi * 16 + frl) * AP + fgr * 8]);
            #pragma unroll
            for (int ni = 0; ni < 8; ni++) {
                int row  = WN + ni * 16 + frl;
                int slot = fgr ^ (row & 3);
                bfv[ni] = *reinterpret_cast<const bf16x8*>(
                    &sB[cur][row * 32 + slot * 8]);
            }
            #pragma unroll
            for (int mi = 0; mi < 4; mi++)
                #pragma unroll
                for (int ni = 0; ni < 8; ni++)
                    acc[mi][ni] = __builtin_amdgcn_mfma_f32_16x16x32_bf16(
                        af[mi], bfv[ni], acc[mi][ni], 0, 0, 0);
        }

        if (more) {
            asm volatile("s_waitcnt vmcnt(4)" ::: "memory");  // A(t+1) ready
            __builtin_amdgcn_sched_barrier(0);
            cvtWriteA(cur ^ 1);
        }
    }

    // GELU + bf16 transposed (c,n,m). C/D: col=lane&15, row=(lane>>4)*4+reg
    #pragma unroll
    for (int mi = 0; mi < 4; mi++)
        #pragma unroll
        for (int ni = 0; ni < 8; ni++) {
            f32x4 v = acc[mi][ni];
            v[0] = gelu_exact(v[0]); v[1] = gelu_exact(v[1]);
            v[2] = gelu_exact(v[2]); v[3] = gelu_exact(v[3]);
            int mrow = m0 + WM + mi * 16 + fgr * 4;
            int ncol = n0 + WN + ni * 16 + frl;
            ushort4 h;
            h.x = f2bf(v[0]); h.y = f2bf(v[1]);
            h.z = f2bf(v[2]); h.w = f2bf(v[3]);
            *reinterpret_cast<ushort4*>(
                &Outb[((size_t)c * 512 + ncol) * M + mrow]) = h;
        }
}

// ---------------------------------------------------------------------------
// MFMA flash attention (unchanged from round 3).
// ---------------------------------------------------------------------------
__global__ __launch_bounds__(256) void attn_mfma_k(
    const unsigned short* __restrict__ pt, const float* __restrict__ fr,
    unsigned short* __restrict__ ot)
{
    int ch = blockIdx.y;
    int c  = ch >> 4, h = ch & 15;
    int q0 = blockIdx.x * 64;
    int t  = threadIdx.x;
    int lane = t & 63;
    int wid  = t >> 6;
    int frl  = lane & 15, fgr = lane >> 4;

    const unsigned short* base = pt + (size_t)c * WW * FF + h * DD;

    __shared__ unsigned short Qs[64 * 72];
    __shared__ unsigned short Ks[64 * 72];
    __shared__ unsigned short Vt[64 * 72];
    __shared__ unsigned short Ps[4 * 16 * 72];

    {
        int kr = t >> 3, d0 = (t & 7) * 8;
        #pragma unroll
        for (int r = 0; r < 2; r++) {
            int row = kr + r * 32;
            int w   = q0 + row;
            bf16x8 v = *reinterpret_cast<const bf16x8*>(&base[(size_t)w * FF + d0]);
            bf16x8 o;
            if (d0 < 32) {
                #pragma unroll
                for (int j = 0; j < 8; j += 2) {
                    float x1 = bf2f((unsigned short)v[j]);
                    float x2 = bf2f((unsigned short)v[j + 1]);
                    float sn, cs;
                    __sincosf((float)w * fr[(d0 + j) >> 1], &sn, &cs);
                    o[j]     = (short)f2bf(x1 * cs - x2 * sn);
                    o[j + 1] = (short)f2bf(x2 * cs + x1 * sn);
                }
            } else o = v;
            *reinterpret_cast<bf16x8*>(&Qs[row * 72 + d0]) = o;
        }
    }

    f32x4 oacc[4];
    float m_[4], l_[4];
    #pragma unroll
    for (int i = 0; i < 4; i++) {
        oacc[i] = (f32x4){0.f, 0.f, 0.f, 0.f};
        m_[i] = -1e30f; l_[i] = 0.f;
    }
    unsigned short* myP = &Ps[wid * 16 * 72];
    int wq0 = wid * 16;

    for (int k0 = 0; k0 < WW; k0 += 64) {
        __syncthreads();
        {
            int kr = t >> 3, d0 = (t & 7) * 8;
            #pragma unroll
            for (int r = 0; r < 2; r++) {
                int row = kr + r * 32;
                int w   = k0 + row;
                bf16x8 v = *reinterpret_cast<const bf16x8*>(&base[(size_t)w * FF + d0]);
                bf16x8 o;
                if (d0 < 32) {
                    #pragma unroll
                    for (int j = 0; j < 8; j += 2) {
                        float x1 = bf2f((unsigned short)v[j]);
                        float x2 = bf2f((unsigned short)v[j + 1]);
                        float sn, cs;
                        __sincosf((float)w * fr[(d0 + j) >> 1], &sn, &cs);
                        o[j]     = (short)f2bf(x1 * cs - x2 * sn);
                        o[j + 1] = (short)f2bf(x2 * cs + x1 * sn);
                    }
                } else o = v;
                *reinterpret_cast<bf16x8*>(&Ks[row * 72 + d0]) = o;
            }
        }
        {
            int d  = t & 63;
            int kb = (t >> 6) * 8;
            #pragma unroll
            for (int r = 0; r < 2; r++) {
                int kk = kb + r * 32;
                bf16x8 o;
                #pragma unroll
                for (int j = 0; j < 8; j++)
                    o[j] = (short)base[(size_t)(k0 + kk + j) * FF + d];
                *reinterpret_cast<bf16x8*>(&Vt[d * 72 + kk]) = o;
            }
        }
        __syncthreads();

        f32x4 s[4];
        #pragma unroll
        for (int nt = 0; nt < 4; nt++) s[nt] = (f32x4){0.f, 0.f, 0.f, 0.f};
        bf16x8 aq0 = *reinterpret_cast<const bf16x8*>(&Qs[(wq0 + frl) * 72 + fgr * 8]);
        bf16x8 aq1 = *reinterpret_cast<const bf16x8*>(&Qs[(wq0 + frl) * 72 + 32 + fgr * 8]);
        #pragma unroll
        for (int nt = 0; nt < 4; nt++) {
            bf16x8 b0 = *reinterpret_cast<const bf16x8*>(&Ks[(nt * 16 + frl) * 72 + fgr * 8]);
            bf16x8 b1 = *reinterpret_cast<const bf16x8*>(&Ks[(nt * 16 + frl) * 72 + 32 + fgr * 8]);
            s[nt] = __builtin_amdgcn_mfma_f32_16x16x32_bf16(aq0, b0, s[nt], 0, 0, 0);
            s[nt] = __builtin_amdgcn_mfma_f32_16x16x32_bf16(aq1, b1, s[nt], 0, 0, 0);
        }

        #pragma unroll
        for (int r = 0; r < 4; r++) {
            float sv[4];
            #pragma unroll
            for (int nt = 0; nt < 4; nt++) sv[nt] = s[nt][r] * (1.f / 32.f);
            float mx = fmaxf(fmaxf(sv[0], sv[1]), fmaxf(sv[2], sv[3]));
            mx = fmaxf(mx, __shfl_xor(mx, 1, 64));
            mx = fmaxf(mx, __shfl_xor(mx, 2, 64));
            mx = fmaxf(mx, __shfl_xor(mx, 4, 64));
            mx = fmaxf(mx, __shfl_xor(mx, 8, 64));
            float mn    = fmaxf(m_[r], mx);
            float scale = __expf(m_[r] - mn);
            float rs = 0.f;
            #pragma unroll
            for (int nt = 0; nt < 4; nt++) {
                float p = __expf(sv[nt] - mn);
                myP[(fgr * 4 + r) * 72 + nt * 16 + frl] = f2bf(p);
                rs += p;
            }
            rs += __shfl_xor(rs, 1, 64);
            rs += __shfl_xor(rs, 2, 64);
            rs += __shfl_xor(rs, 4, 64);
            rs += __shfl_xor(rs, 8, 64);
            l_[r] = l_[r] * scale + rs;
            m_[r] = mn;
            #pragma unroll
            for (int dt = 0; dt < 4; dt++) oacc[dt][r] *= scale;
        }

        bf16x8 ap0 = *reinterpret_cast<const bf16x8*>(&myP[frl * 72 + fgr * 8]);
        bf16x8 ap1 = *reinterpret_cast<const bf16x8*>(&myP[frl * 72 + 32 + fgr * 8]);
        #pragma unroll
        for (int dt = 0; dt < 4; dt++) {
            bf16x8 b0 = *reinterpret_cast<const bf16x8*>(&Vt[(dt * 16 + frl) * 72 + fgr * 8]);
            bf16x8 b1 = *reinterpret_cast<const bf16x8*>(&Vt[(dt * 16 + frl) * 72 + 32 + fgr * 8]);
            oacc[dt] = __builtin_amdgcn_mfma_f32_16x16x32_bf16(ap0, b0, oacc[dt], 0, 0, 0);
            oacc[dt] = __builtin_amdgcn_mfma_f32_16x16x32_bf16(ap1, b1, oacc[dt], 0, 0, 0);
        }
    }

    unsigned short* ob = ot + (size_t)c * WW * FF + h * DD;
    #pragma unroll
    for (int r = 0; r < 4; r++) {
        float inv = 1.f / l_[r];
        int w = q0 + wq0 + fgr * 4 + r;
        #pragma unroll
        for (int dt = 0; dt < 4; dt++)
            ob[(size_t)w * FF + dt * 16 + frl] = f2bf(oacc[dt][r] * inv);
    }
}

// ---------------------------------------------------------------------------
extern "C" void kernel_launch(void* const* d_in, const int* in_sizes, int n_in,
                              void* d_out, int out_size, void* d_ws, size_t ws_size,
                              hipStream_t stream)
{
    const float* x  = (const float*)d_in[0];
    const float* g1 = (const float*)d_in[1];
    const float* b1 = (const float*)d_in[2];
    const float* wq = (const float*)d_in[3];
    const float* wo = (const float*)d_in[4];
    const float* fr = (const float*)d_in[5];
    const float* g2 = (const float*)d_in[6];
    const float* b2 = (const float*)d_in[7];
    const float* w1 = (const float*)d_in[8];
    const float* w2 = (const float*)d_in[9];

    const size_t SZ = (size_t)CC * FF * WW;
    char* wsb = (char*)d_ws;
    unsigned short* zt  = (unsigned short*)(wsb);            // bf16 (c,w,f)
    unsigned short* ptb = (unsigned short*)(wsb + 2 * SZ);   // bf16 (c,w,f)
    unsigned short* otb = (unsigned short*)(wsb + 4 * SZ);   // bf16 (c,w,f)
    float*          x2  = (float*)        (wsb + 6 * SZ);    // fp32 (c,f,w)
    unsigned short* h1t = (unsigned short*)(wsb + 10 * SZ);  // bf16 (c,w,4096)
    float2*         prt = (float2*)       (wsb + 18 * SZ);   // stats partials

    dim3 b256(256);
    dim3 gst(WW / 64, FF / 128, CC);
    dim3 gap(WW / 64, FF / 64, CC);

    // 1. zt = frame_norm(x)^T (bf16)
    fn_stats_k<<<gst, b256, 0, stream>>>(x, prt);
    fn_apply_k<<<gap, b256, 0, stream>>>(x, prt, g1, b1, zt);
    // 2. ptb = (wq . z)^T — grid 512
    gemm_v6_k<64, 3><<<dim3(512), b256, 0, stream>>>(
        wq, zt, nullptr, ptb, nullptr, FF, FF, 0);
    // 3. attention (rope fused) -> otb (c,w,f) bf16
    attn_mfma_k<<<dim3(WW / 64, CC * HH), b256, 0, stream>>>(ptb, fr, otb);
    // 4. x2 = x + wo . o
    gemm_v6_k<64, 3><<<dim3(512), b256, 0, stream>>>(
        wo, otb, x2, nullptr, x, FF, FF, 1);
    // 5. zt = frame_norm(x2)^T
    fn_stats_k<<<gst, b256, 0, stream>>>(x2, prt);
    fn_apply_k<<<gap, b256, 0, stream>>>(x2, prt, g2, b2, zt);
    // 6. h1t = gelu(w1 . z2)^T — big-wave kernel, grid 8 x 2 x 32 = 512
    gemm_w1big_k<<<dim3(512), b256, 0, stream>>>(w1, zt, h1t, FE, FF);
    // 7. out = x2 + w2 . h1 — grid 512, K=4096
    gemm_v6_k<64, 3><<<dim3(512), b256, 0, stream>>>(
        w2, h1t, (float*)d_out, nullptr, x2, FF, FE, 1);
}